// Round 1
// baseline (1176.424 us; speedup 1.0000x reference)
//
#include <hip/hip_runtime.h>

#define N_NODES 131072
#define D 128
#define NLAYERS 4

// ---------------- embed: feats[v] = emb[node_idx[v]] ----------------
__global__ __launch_bounds__(256) void embed_kernel(
    const int* __restrict__ node_idx, const float* __restrict__ emb,
    float* __restrict__ feats)
{
    int i = blockIdx.x * 256 + threadIdx.x;   // float4 index, grid sized exactly
    int v = i >> 5;                           // node
    int c = i & 31;                           // float4 within row (32 per row)
    int tok = node_idx[v];
    ((float4*)feats)[(size_t)v * 32 + c] =
        ((const float4*)emb)[(size_t)tok * 32 + c];
}

// ---------------- layer GEMM1: h = relu(gather(feats) @ W0 + b0) ----------------
// Tile: BM=64 nodes x BN=128 cols, BK=64, K=512 (4 neighbor slots x 128).
// Gather is fused into the A-tile staging; pad node (id==N_NODES) -> zeros.
__global__ __launch_bounds__(256) void gather_gemm1(
    const float* __restrict__ feats, const int* __restrict__ neighbors,
    const float* __restrict__ W0, const float* __restrict__ b0,
    float* __restrict__ h)
{
    __shared__ __align__(16) float As[64][68];   // [kk][row], stride 68 kills conflicts
    __shared__ __align__(16) float Bs[64][128];  // [kk][col]
    __shared__ int nbr_s[256];                   // 64 rows x 4 slots

    const int tid = threadIdx.x;
    const int bm  = blockIdx.x * 64;

    nbr_s[tid] = neighbors[bm * 4 + tid];        // coalesced, 256 ints

    const int ty   = tid >> 4;    // 0..15: row group (4 rows each)
    const int tx   = tid & 15;    // 0..15: col group (cols tx*4.. and 64+tx*4..)
    const int lrow = tid & 63;    // staging row
    const int lseg = tid >> 6;    // staging 16-float segment

    float acc[4][8];
#pragma unroll
    for (int i = 0; i < 4; ++i)
#pragma unroll
        for (int j = 0; j < 8; ++j) acc[i][j] = 0.f;

    __syncthreads();

    for (int kc = 0; kc < 8; ++kc) {
        // ---- stage A tile (gathered) ----
        {
            const int e    = kc >> 1;
            const int koff = (kc & 1) * 64;
            const int nbr  = nbr_s[lrow * 4 + e];
            float4 v0, v1, v2, v3;
            if (nbr < N_NODES) {
                const float4* src =
                    (const float4*)(feats + (size_t)nbr * D + koff + lseg * 16);
                v0 = src[0]; v1 = src[1]; v2 = src[2]; v3 = src[3];
            } else {
                v0 = v1 = v2 = v3 = make_float4(0.f, 0.f, 0.f, 0.f);
            }
            float tmp[16];
            *(float4*)&tmp[0]  = v0; *(float4*)&tmp[4]  = v1;
            *(float4*)&tmp[8]  = v2; *(float4*)&tmp[12] = v3;
            const int kk0 = lseg * 16;
#pragma unroll
            for (int j = 0; j < 16; ++j) As[kk0 + j][lrow] = tmp[j];
        }
        // ---- stage B tile: W0 rows kc*64..kc*64+63, all 128 cols ----
        {
            const float4* src = (const float4*)(W0 + (size_t)kc * 64 * D);
            float4* dst = (float4*)&Bs[0][0];
#pragma unroll
            for (int i = 0; i < 8; ++i) dst[i * 256 + tid] = src[i * 256 + tid];
        }
        __syncthreads();
        // ---- compute ----
#pragma unroll 8
        for (int kk = 0; kk < 64; ++kk) {
            float4 a  = *(const float4*)&As[kk][ty * 4];
            float4 bl = *(const float4*)&Bs[kk][tx * 4];
            float4 bh = *(const float4*)&Bs[kk][64 + tx * 4];
            const float av[4] = {a.x, a.y, a.z, a.w};
            const float bv[8] = {bl.x, bl.y, bl.z, bl.w, bh.x, bh.y, bh.z, bh.w};
#pragma unroll
            for (int i = 0; i < 4; ++i)
#pragma unroll
                for (int j = 0; j < 8; ++j) acc[i][j] += av[i] * bv[j];
        }
        __syncthreads();
    }

    // ---- epilogue: bias + relu, write h ----
    const int c0 = tx * 4, c1 = 64 + tx * 4;
    float4 bias0 = *(const float4*)&b0[c0];
    float4 bias1 = *(const float4*)&b0[c1];
    const float bb[8] = {bias0.x, bias0.y, bias0.z, bias0.w,
                         bias1.x, bias1.y, bias1.z, bias1.w};
#pragma unroll
    for (int i = 0; i < 4; ++i) {
        const int r = bm + ty * 4 + i;
        float4 o0, o1;
        o0.x = fmaxf(acc[i][0] + bb[0], 0.f);
        o0.y = fmaxf(acc[i][1] + bb[1], 0.f);
        o0.z = fmaxf(acc[i][2] + bb[2], 0.f);
        o0.w = fmaxf(acc[i][3] + bb[3], 0.f);
        o1.x = fmaxf(acc[i][4] + bb[4], 0.f);
        o1.y = fmaxf(acc[i][5] + bb[5], 0.f);
        o1.z = fmaxf(acc[i][6] + bb[6], 0.f);
        o1.w = fmaxf(acc[i][7] + bb[7], 0.f);
        *(float4*)&h[(size_t)r * D + c0] = o0;
        *(float4*)&h[(size_t)r * D + c1] = o1;
    }
}

// ---------------- layer GEMM2: feats = h @ W1 + b1 ----------------
__global__ __launch_bounds__(256) void gemm2(
    const float* __restrict__ hin, const float* __restrict__ W1,
    const float* __restrict__ b1, float* __restrict__ fout)
{
    __shared__ __align__(16) float As[64][68];
    __shared__ __align__(16) float Bs[64][128];

    const int tid = threadIdx.x;
    const int bm  = blockIdx.x * 64;

    const int ty   = tid >> 4;
    const int tx   = tid & 15;
    const int lrow = tid & 63;
    const int lseg = tid >> 6;

    float acc[4][8];
#pragma unroll
    for (int i = 0; i < 4; ++i)
#pragma unroll
        for (int j = 0; j < 8; ++j) acc[i][j] = 0.f;

    for (int kc = 0; kc < 2; ++kc) {
        {
            const float4* src = (const float4*)(hin + (size_t)(bm + lrow) * D +
                                                kc * 64 + lseg * 16);
            float4 v0 = src[0], v1 = src[1], v2 = src[2], v3 = src[3];
            float tmp[16];
            *(float4*)&tmp[0]  = v0; *(float4*)&tmp[4]  = v1;
            *(float4*)&tmp[8]  = v2; *(float4*)&tmp[12] = v3;
            const int kk0 = lseg * 16;
#pragma unroll
            for (int j = 0; j < 16; ++j) As[kk0 + j][lrow] = tmp[j];
        }
        {
            const float4* src = (const float4*)(W1 + (size_t)kc * 64 * D);
            float4* dst = (float4*)&Bs[0][0];
#pragma unroll
            for (int i = 0; i < 8; ++i) dst[i * 256 + tid] = src[i * 256 + tid];
        }
        __syncthreads();
#pragma unroll 8
        for (int kk = 0; kk < 64; ++kk) {
            float4 a  = *(const float4*)&As[kk][ty * 4];
            float4 bl = *(const float4*)&Bs[kk][tx * 4];
            float4 bh = *(const float4*)&Bs[kk][64 + tx * 4];
            const float av[4] = {a.x, a.y, a.z, a.w};
            const float bv[8] = {bl.x, bl.y, bl.z, bl.w, bh.x, bh.y, bh.z, bh.w};
#pragma unroll
            for (int i = 0; i < 4; ++i)
#pragma unroll
                for (int j = 0; j < 8; ++j) acc[i][j] += av[i] * bv[j];
        }
        __syncthreads();
    }

    const int c0 = tx * 4, c1 = 64 + tx * 4;
    float4 bias0 = *(const float4*)&b1[c0];
    float4 bias1 = *(const float4*)&b1[c1];
    const float bb[8] = {bias0.x, bias0.y, bias0.z, bias0.w,
                         bias1.x, bias1.y, bias1.z, bias1.w};
#pragma unroll
    for (int i = 0; i < 4; ++i) {
        const int r = bm + ty * 4 + i;
        float4 o0, o1;
        o0.x = acc[i][0] + bb[0];
        o0.y = acc[i][1] + bb[1];
        o0.z = acc[i][2] + bb[2];
        o0.w = acc[i][3] + bb[3];
        o1.x = acc[i][4] + bb[4];
        o1.y = acc[i][5] + bb[5];
        o1.z = acc[i][6] + bb[6];
        o1.w = acc[i][7] + bb[7];
        *(float4*)&fout[(size_t)r * D + c0] = o0;
        *(float4*)&fout[(size_t)r * D + c1] = o1;
    }
}

// ---------------- readout: per-segment mean + pairwise dot ----------------
__global__ __launch_bounds__(256) void readout_kernel(
    const float* __restrict__ feats, const float* __restrict__ out_bias,
    float* __restrict__ logits)
{
    __shared__ float ms[2][128];
    const int b   = blockIdx.x;      // equation index
    const int tid = threadIdx.x;
    const int side = tid >> 7;       // 0: seg 2b, 1: seg 2b+1
    const int d    = tid & 127;

    const float* base = feats + ((size_t)b * 128 + side * 64) * D + d;
    float s = 0.f;
#pragma unroll 8
    for (int n = 0; n < 64; ++n) s += base[(size_t)n * D];
    ms[side][d] = s * (1.0f / 64.0f);
    __syncthreads();

    if (tid < 64) {
        float v = ms[0][tid] * ms[1][tid] + ms[0][tid + 64] * ms[1][tid + 64];
#pragma unroll
        for (int off = 32; off; off >>= 1) v += __shfl_down(v, off);
        if (tid == 0) logits[b] = v + out_bias[0];
    }
}

extern "C" void kernel_launch(void* const* d_in, const int* in_sizes, int n_in,
                              void* d_out, int out_size, void* d_ws, size_t ws_size,
                              hipStream_t stream) {
    const int*   node_idx  = (const int*)d_in[0];
    const int*   neighbors = (const int*)d_in[1];
    // d_in[2] = seg_ids (implicit: v / 64), unused
    const float* emb       = (const float*)d_in[3];
    const float* W0        = (const float*)d_in[4];
    const float* b0        = (const float*)d_in[5];
    const float* W1        = (const float*)d_in[6];
    const float* b1        = (const float*)d_in[7];
    const float* out_bias  = (const float*)d_in[8];
    float*       logits    = (float*)d_out;

    float* feats = (float*)d_ws;                       // 64 MB
    float* h     = feats + (size_t)N_NODES * D;        // 64 MB

    embed_kernel<<<(N_NODES * 32) / 256, 256, 0, stream>>>(node_idx, emb, feats);

    for (int l = 0; l < NLAYERS; ++l) {
        gather_gemm1<<<N_NODES / 64, 256, 0, stream>>>(
            feats, neighbors, W0 + (size_t)l * 512 * 128, b0 + (size_t)l * 128, h);
        gemm2<<<N_NODES / 64, 256, 0, stream>>>(
            h, W1 + (size_t)l * 128 * 128, b1 + (size_t)l * 128, feats);
    }

    readout_kernel<<<N_NODES / 128, 256, 0, stream>>>(feats, out_bias, logits);
}

// Round 2
// 349.877 us; speedup vs baseline: 3.3624x; 3.3624x over previous
//
#include <hip/hip_runtime.h>

#define N_NODES 131072
#define D 128
#define NLAYERS 4
#define LDS_STRIDE 72   // 64 + 8 f16 pad -> 144 B rows, conflict-free-ish

typedef _Float16 f16;
typedef _Float16 f16x8 __attribute__((ext_vector_type(8)));
typedef _Float16 f16x4 __attribute__((ext_vector_type(4)));
typedef float f32x4 __attribute__((ext_vector_type(4)));

// ---------- prep: W0t[l][n][k]=f16(W0[l][k][n]), W1t likewise ----------
__global__ __launch_bounds__(256) void prep_weights(
    const float* __restrict__ W0, const float* __restrict__ W1,
    f16* __restrict__ W0t, f16* __restrict__ W1t)
{
    __shared__ float T[64][65];
    int b = blockIdx.x;
    const float* src; f16* dst; int K, tk, tn;
    if (b < 64) {                       // W0: 4 layers x (8 k-tiles x 2 n-tiles)
        int l = b >> 4; tk = (b >> 1) & 7; tn = b & 1;
        src = W0 + (size_t)l * 512 * 128; dst = W0t + (size_t)l * 128 * 512; K = 512;
    } else {                            // W1: 4 layers x (2 x 2)
        int bb = b - 64; int l = bb >> 2; tk = (bb >> 1) & 1; tn = bb & 1;
        src = W1 + (size_t)l * 128 * 128; dst = W1t + (size_t)l * 128 * 128; K = 128;
    }
    const int tid = threadIdx.x;
#pragma unroll
    for (int i = 0; i < 16; ++i) {
        int u = tid + 256 * i;          // 4096 elems
        int kk = u >> 6, nn = u & 63;
        T[kk][nn] = src[(size_t)(tk * 64 + kk) * 128 + tn * 64 + nn];
    }
    __syncthreads();
#pragma unroll
    for (int i = 0; i < 16; ++i) {
        int u = tid + 256 * i;
        int nn = u >> 6, kk = u & 63;
        dst[(size_t)(tn * 64 + nn) * K + tk * 64 + kk] = (f16)T[kk][nn];
    }
}

// ---------- embed: feats[v] = f16(emb[node_idx[v]]) ----------
__global__ __launch_bounds__(256) void embed_f16(
    const int* __restrict__ node_idx, const float* __restrict__ emb,
    f16* __restrict__ feats)
{
    int i = blockIdx.x * 256 + threadIdx.x;   // N*32 float4-groups
    int v = i >> 5, c = i & 31;
    int tok = node_idx[v];
    float4 x = ((const float4*)emb)[(size_t)tok * 32 + c];
    f16x4 y = { (f16)x.x, (f16)x.y, (f16)x.z, (f16)x.w };
    *(f16x4*)&feats[(size_t)v * D + c * 4] = y;
}

// ---------- fused layer: h=relu(gather(fin)@W0+b0); fout=h@W1+b1 ----------
__global__ __launch_bounds__(256, 3) void layer_fused(
    const f16* __restrict__ fin, f16* __restrict__ fout,
    const int* __restrict__ neighbors,
    const f16* __restrict__ W0t, const float* __restrict__ b0,
    const f16* __restrict__ W1t, const float* __restrict__ b1)
{
    __shared__ f16 As[128][LDS_STRIDE];
    __shared__ f16 Bs[128][LDS_STRIDE];
    __shared__ int nbr_s[512];

    const int tid  = threadIdx.x;
    const int bm   = blockIdx.x * 128;
    const int lane = tid & 63;
    const int wave = tid >> 6;
    const int wr = wave >> 1, wc = wave & 1;     // 2x2 wave grid, 64x64 each
    const int quad = lane >> 4, lm = lane & 15;

    nbr_s[tid]       = neighbors[bm * 4 + tid];
    nbr_s[tid + 256] = neighbors[bm * 4 + 256 + tid];

    f32x4 acc1[4][4];
#pragma unroll
    for (int r = 0; r < 4; ++r)
#pragma unroll
        for (int c = 0; c < 4; ++c) acc1[r][c] = (f32x4){0.f, 0.f, 0.f, 0.f};

    // ---------------- phase 1: K = 512 in 8 chunks of 64 ----------------
    for (int kc = 0; kc < 8; ++kc) {
        const int e = kc >> 1, koff = (kc & 1) * 64;
        __syncthreads();
        // stage gathered A (128 rows x 64 k), 16 B units
#pragma unroll
        for (int i = 0; i < 4; ++i) {
            int u = tid + 256 * i;               // 1024 units
            int row = u >> 3, seg = u & 7;
            int nbr = nbr_s[row * 4 + e];
            f16x8 v = {0, 0, 0, 0, 0, 0, 0, 0};
            if (nbr < N_NODES)
                v = *(const f16x8*)&fin[(size_t)nbr * D + koff + seg * 8];
            *(f16x8*)&As[row][seg * 8] = v;
        }
        // stage B = W0t chunk (128 cols x 64 k)
#pragma unroll
        for (int i = 0; i < 4; ++i) {
            int u = tid + 256 * i;
            int col = u >> 3, seg = u & 7;
            *(f16x8*)&Bs[col][seg * 8] =
                *(const f16x8*)&W0t[(size_t)col * 512 + kc * 64 + seg * 8];
        }
        __syncthreads();
#pragma unroll
        for (int t = 0; t < 2; ++t) {
            const int k0 = t * 32 + quad * 8;
            f16x8 af[4], bf[4];
#pragma unroll
            for (int r = 0; r < 4; ++r)
                af[r] = *(const f16x8*)&As[wr * 64 + r * 16 + lm][k0];
#pragma unroll
            for (int c = 0; c < 4; ++c)
                bf[c] = *(const f16x8*)&Bs[wc * 64 + c * 16 + lm][k0];
#pragma unroll
            for (int r = 0; r < 4; ++r)
#pragma unroll
                for (int c = 0; c < 4; ++c)
                    acc1[r][c] = __builtin_amdgcn_mfma_f32_16x16x32_f16(
                        af[r], bf[c], acc1[r][c], 0, 0, 0);
        }
    }

    // bias + relu -> h packed to f16 pairs (frees acc1's 64 VGPRs down to 32)
    unsigned int hpk[4][4][2];
#pragma unroll
    for (int c = 0; c < 4; ++c) {
        float b0v = b0[wc * 64 + c * 16 + lm];
#pragma unroll
        for (int r = 0; r < 4; ++r) {
#pragma unroll
            for (int p = 0; p < 2; ++p) {
                float v0 = fmaxf(acc1[r][c][2 * p]     + b0v, 0.f);
                float v1 = fmaxf(acc1[r][c][2 * p + 1] + b0v, 0.f);
                unsigned short u0 = __builtin_bit_cast(unsigned short, (f16)v0);
                unsigned short u1 = __builtin_bit_cast(unsigned short, (f16)v1);
                hpk[r][c][p] = ((unsigned)u1 << 16) | u0;
            }
        }
    }

    // ---------------- phase 2: fout_tile = h @ W1t, K = 128 in 2 chunks ----
    f32x4 acc2[4][4];
#pragma unroll
    for (int r = 0; r < 4; ++r)
#pragma unroll
        for (int c = 0; c < 4; ++c) acc2[r][c] = (f32x4){0.f, 0.f, 0.f, 0.f};

    for (int kc2 = 0; kc2 < 2; ++kc2) {
        __syncthreads();
        if (wc == kc2) {   // waves owning these h columns write them as A
#pragma unroll
            for (int r = 0; r < 4; ++r)
#pragma unroll
                for (int c = 0; c < 4; ++c) {
                    int klocal = c * 16 + lm;
#pragma unroll
                    for (int reg = 0; reg < 4; ++reg) {
                        int row = wr * 64 + r * 16 + quad * 4 + reg;
                        unsigned pk = hpk[r][c][reg >> 1];
                        unsigned short bits =
                            (reg & 1) ? (unsigned short)(pk >> 16)
                                      : (unsigned short)(pk & 0xffff);
                        As[row][klocal] = __builtin_bit_cast(f16, bits);
                    }
                }
        }
#pragma unroll
        for (int i = 0; i < 4; ++i) {
            int u = tid + 256 * i;
            int col = u >> 3, seg = u & 7;
            *(f16x8*)&Bs[col][seg * 8] =
                *(const f16x8*)&W1t[(size_t)col * 128 + kc2 * 64 + seg * 8];
        }
        __syncthreads();
#pragma unroll
        for (int t = 0; t < 2; ++t) {
            const int k0 = t * 32 + quad * 8;
            f16x8 af[4], bf[4];
#pragma unroll
            for (int r = 0; r < 4; ++r)
                af[r] = *(const f16x8*)&As[wr * 64 + r * 16 + lm][k0];
#pragma unroll
            for (int c = 0; c < 4; ++c)
                bf[c] = *(const f16x8*)&Bs[wc * 64 + c * 16 + lm][k0];
#pragma unroll
            for (int r = 0; r < 4; ++r)
#pragma unroll
                for (int c = 0; c < 4; ++c)
                    acc2[r][c] = __builtin_amdgcn_mfma_f32_16x16x32_f16(
                        af[r], bf[c], acc2[r][c], 0, 0, 0);
        }
    }

    // ---- epilogue: bounce through LDS for coalesced 16B f16 stores ----
    __syncthreads();
#pragma unroll
    for (int r = 0; r < 4; ++r)
#pragma unroll
        for (int c = 0; c < 4; ++c) {
            float b1v = b1[wc * 64 + c * 16 + lm];
            int col = c * 16 + lm;               // local col within 64-col half
#pragma unroll
            for (int reg = 0; reg < 4; ++reg) {
                int row = wr * 64 + r * 16 + quad * 4 + reg;
                f16 v = (f16)(acc2[r][c][reg] + b1v);
                if (wc == 0) As[row][col] = v;
                else         Bs[row][col] = v;
            }
        }
    __syncthreads();
#pragma unroll
    for (int i = 0; i < 8; ++i) {
        int u = tid + 256 * i;                   // 2048 x 16B units
        int row = u >> 4, seg = u & 15;
        f16x8 v = (seg < 8) ? *(const f16x8*)&As[row][seg * 8]
                            : *(const f16x8*)&Bs[row][(seg - 8) * 8];
        *(f16x8*)&fout[(size_t)(bm + row) * D + seg * 8] = v;
    }
}

// ---------- readout: per-segment mean + pairwise dot ----------
__global__ __launch_bounds__(256) void readout_f16(
    const f16* __restrict__ feats, const float* __restrict__ out_bias,
    float* __restrict__ logits)
{
    __shared__ float ms[2][128];
    const int b   = blockIdx.x;
    const int tid = threadIdx.x;
    const int side = tid >> 7, d = tid & 127;

    const f16* base = feats + ((size_t)b * 128 + side * 64) * D + d;
    float s = 0.f;
#pragma unroll 8
    for (int n = 0; n < 64; ++n) s += (float)base[(size_t)n * D];
    ms[side][d] = s * (1.0f / 64.0f);
    __syncthreads();

    if (tid < 64) {
        float v = ms[0][tid] * ms[1][tid] + ms[0][tid + 64] * ms[1][tid + 64];
#pragma unroll
        for (int off = 32; off; off >>= 1) v += __shfl_down(v, off);
        if (tid == 0) logits[b] = v + out_bias[0];
    }
}

extern "C" void kernel_launch(void* const* d_in, const int* in_sizes, int n_in,
                              void* d_out, int out_size, void* d_ws, size_t ws_size,
                              hipStream_t stream) {
    const int*   node_idx  = (const int*)d_in[0];
    const int*   neighbors = (const int*)d_in[1];
    const float* emb       = (const float*)d_in[3];
    const float* W0        = (const float*)d_in[4];
    const float* b0        = (const float*)d_in[5];
    const float* W1        = (const float*)d_in[6];
    const float* b1        = (const float*)d_in[7];
    const float* out_bias  = (const float*)d_in[8];
    float*       logits    = (float*)d_out;

    f16* feats_a = (f16*)d_ws;                               // 32 MB
    f16* feats_b = feats_a + (size_t)N_NODES * D;            // 32 MB
    f16* W0t     = feats_b + (size_t)N_NODES * D;            // 512 KB
    f16* W1t     = W0t + (size_t)NLAYERS * 512 * 128;        // 128 KB

    prep_weights<<<80, 256, 0, stream>>>(W0, W1, W0t, W1t);
    embed_f16<<<(N_NODES * 32) / 256, 256, 0, stream>>>(node_idx, emb, feats_a);

    f16* fin = feats_a; f16* fout = feats_b;
    for (int l = 0; l < NLAYERS; ++l) {
        layer_fused<<<N_NODES / 128, 256, 0, stream>>>(
            fin, fout, neighbors,
            W0t + (size_t)l * 512 * 128, b0 + (size_t)l * 128,
            W1t + (size_t)l * 128 * 128, b1 + (size_t)l * 128);
        f16* t = fin; fin = fout; fout = t;
    }
    // after 4 swaps the final features are back in feats_a
    readout_f16<<<N_NODES / 128, 256, 0, stream>>>(feats_a, out_bias, logits);
}

// Round 3
// 244.849 us; speedup vs baseline: 4.8047x; 1.4289x over previous
//
#include <hip/hip_runtime.h>

#define N_NODES 131072
#define D 128
#define NLAYERS 4
#define AS_STRIDE 136   // 128 + 8 f16 pad -> 272 B rows: 16B-aligned, even bank groups

typedef _Float16 f16;
typedef _Float16 f16x8 __attribute__((ext_vector_type(8)));
typedef _Float16 f16x4 __attribute__((ext_vector_type(4)));
typedef float f32x4 __attribute__((ext_vector_type(4)));

// ---------- prep: W0t[l][n][k]=f16(W0[l][k][n]), W1t likewise ----------
__global__ __launch_bounds__(256) void prep_weights(
    const float* __restrict__ W0, const float* __restrict__ W1,
    f16* __restrict__ W0t, f16* __restrict__ W1t)
{
    __shared__ float T[64][65];
    int b = blockIdx.x;
    const float* src; f16* dst; int K, tk, tn;
    if (b < 64) {                       // W0: 4 layers x (8 k-tiles x 2 n-tiles)
        int l = b >> 4; tk = (b >> 1) & 7; tn = b & 1;
        src = W0 + (size_t)l * 512 * 128; dst = W0t + (size_t)l * 128 * 512; K = 512;
    } else {                            // W1: 4 layers x (2 x 2)
        int bb = b - 64; int l = bb >> 2; tk = (bb >> 1) & 1; tn = bb & 1;
        src = W1 + (size_t)l * 128 * 128; dst = W1t + (size_t)l * 128 * 128; K = 128;
    }
    const int tid = threadIdx.x;
#pragma unroll
    for (int i = 0; i < 16; ++i) {
        int u = tid + 256 * i;          // 4096 elems
        int kk = u >> 6, nn = u & 63;
        T[kk][nn] = src[(size_t)(tk * 64 + kk) * 128 + tn * 64 + nn];
    }
    __syncthreads();
#pragma unroll
    for (int i = 0; i < 16; ++i) {
        int u = tid + 256 * i;
        int nn = u >> 6, kk = u & 63;
        dst[(size_t)(tn * 64 + nn) * K + tk * 64 + kk] = (f16)T[kk][nn];
    }
}

// ---------- embed: feats[v] = f16(emb[node_idx[v]]); also zero pad rows ----------
__global__ __launch_bounds__(256) void embed_f16(
    const int* __restrict__ node_idx, const float* __restrict__ emb,
    f16* __restrict__ fa, f16* __restrict__ fb)
{
    const int tid = threadIdx.x;
    if (blockIdx.x == 16384) {          // zero the padding row (id N_NODES) of both buffers
        if (tid < 32) {
            f16x8 z = {0, 0, 0, 0, 0, 0, 0, 0};
            f16* base = (tid >> 4) ? fb : fa;
            *(f16x8*)&base[(size_t)N_NODES * D + (tid & 15) * 8] = z;
        }
        return;
    }
    int i = blockIdx.x * 256 + tid;     // N*32 float4-groups
    int v = i >> 5, c = i & 31;
    int tok = node_idx[v];
    float4 x = ((const float4*)emb)[(size_t)tok * 32 + c];
    f16x4 y = { (f16)x.x, (f16)x.y, (f16)x.z, (f16)x.w };
    *(f16x4*)&fa[(size_t)v * D + c * 4] = y;
}

// ---------- fused layer: h=relu(gather(fin)@W0+b0); fout=h@W1+b1 ----------
// Register-prefetch pipeline: stage e+1's gather + weights load into VGPRs
// while stage e's MFMAs run from LDS; written to LDS after the barrier.
__global__ __launch_bounds__(256, 2) void layer_fused(
    const f16* __restrict__ fin, f16* __restrict__ fout,
    const int* __restrict__ neighbors,
    const f16* __restrict__ W0t, const float* __restrict__ b0,
    const f16* __restrict__ W1t, const float* __restrict__ b1)
{
    __shared__ f16 As[128][AS_STRIDE];
    __shared__ f16 Bs[128][AS_STRIDE];
    __shared__ int nbr_s[512];

    const int tid  = threadIdx.x;
    const int bm   = blockIdx.x * 128;
    const int lane = tid & 63;
    const int wave = tid >> 6;
    const int wr = wave >> 1, wc = wave & 1;     // 2x2 wave grid, 64x64 each
    const int quad = lane >> 4, lm = lane & 15;
    const int seg = tid & 15, r0 = tid >> 4;     // staging coords (16 segs/row)

    nbr_s[tid]       = neighbors[bm * 4 + tid];
    nbr_s[tid + 256] = neighbors[bm * 4 + 256 + tid];

    float bb0[4], bb1[4];
#pragma unroll
    for (int c = 0; c < 4; ++c) {
        bb0[c] = b0[wc * 64 + c * 16 + lm];
        bb1[c] = b1[wc * 64 + c * 16 + lm];
    }

    f16x8 ra[8], rb[8];
    __syncthreads();                             // nbr_s ready

    // prefetch stage 0
#pragma unroll
    for (int i = 0; i < 8; ++i) {
        int row = r0 + 16 * i;
        int nbr = nbr_s[row * 4 + 0];
        ra[i] = *(const f16x8*)&fin[(size_t)nbr * D + seg * 8];
        rb[i] = *(const f16x8*)&W0t[(size_t)row * 512 + seg * 8];
    }
#pragma unroll
    for (int i = 0; i < 8; ++i) {
        int row = r0 + 16 * i;
        *(f16x8*)&As[row][seg * 8] = ra[i];
        *(f16x8*)&Bs[row][seg * 8] = rb[i];
    }
    __syncthreads();

    f32x4 acc1[4][4];
#pragma unroll
    for (int r = 0; r < 4; ++r)
#pragma unroll
        for (int c = 0; c < 4; ++c) acc1[r][c] = (f32x4){0.f, 0.f, 0.f, 0.f};

    // ---------------- phase 1: 4 stages of K=128 (one neighbor slot each) ----
    for (int e = 0; e < 4; ++e) {
        // prefetch next stage (or phase-2 W1t on the last stage)
        if (e < 3) {
#pragma unroll
            for (int i = 0; i < 8; ++i) {
                int row = r0 + 16 * i;
                int nbr = nbr_s[row * 4 + e + 1];
                ra[i] = *(const f16x8*)&fin[(size_t)nbr * D + seg * 8];
                rb[i] = *(const f16x8*)&W0t[(size_t)row * 512 + (e + 1) * 128 + seg * 8];
            }
        } else {
#pragma unroll
            for (int i = 0; i < 8; ++i) {
                int row = r0 + 16 * i;
                rb[i] = *(const f16x8*)&W1t[(size_t)row * 128 + seg * 8];
            }
        }
        // compute stage e from LDS
#pragma unroll
        for (int t = 0; t < 4; ++t) {
            const int k0 = t * 32 + quad * 8;
            f16x8 af[4], bf[4];
#pragma unroll
            for (int r = 0; r < 4; ++r)
                af[r] = *(const f16x8*)&As[wr * 64 + r * 16 + lm][k0];
#pragma unroll
            for (int c = 0; c < 4; ++c)
                bf[c] = *(const f16x8*)&Bs[wc * 64 + c * 16 + lm][k0];
#pragma unroll
            for (int r = 0; r < 4; ++r)
#pragma unroll
                for (int c = 0; c < 4; ++c)
                    acc1[r][c] = __builtin_amdgcn_mfma_f32_16x16x32_f16(
                        af[r], bf[c], acc1[r][c], 0, 0, 0);
        }
        __syncthreads();                          // all LDS reads of stage e done
        if (e < 3) {
#pragma unroll
            for (int i = 0; i < 8; ++i) {
                int row = r0 + 16 * i;
                *(f16x8*)&As[row][seg * 8] = ra[i];
                *(f16x8*)&Bs[row][seg * 8] = rb[i];
            }
            __syncthreads();
        }
    }

    // bias + relu -> h packed to f16 pairs
    unsigned int hpk[4][4][2];
#pragma unroll
    for (int c = 0; c < 4; ++c) {
#pragma unroll
        for (int r = 0; r < 4; ++r) {
#pragma unroll
            for (int p = 0; p < 2; ++p) {
                float v0 = fmaxf(acc1[r][c][2 * p]     + bb0[c], 0.f);
                float v1 = fmaxf(acc1[r][c][2 * p + 1] + bb0[c], 0.f);
                unsigned short u0 = __builtin_bit_cast(unsigned short, (f16)v0);
                unsigned short u1 = __builtin_bit_cast(unsigned short, (f16)v1);
                hpk[r][c][p] = ((unsigned)u1 << 16) | u0;
            }
        }
    }

    // scatter h (C-layout) into As as phase-2 A operand [row][hcol]; W1t -> Bs
#pragma unroll
    for (int r = 0; r < 4; ++r)
#pragma unroll
        for (int c = 0; c < 4; ++c) {
            int gcol = wc * 64 + c * 16 + lm;
#pragma unroll
            for (int reg = 0; reg < 4; ++reg) {
                int grow = wr * 64 + r * 16 + quad * 4 + reg;
                unsigned pk = hpk[r][c][reg >> 1];
                unsigned short bits = (reg & 1) ? (unsigned short)(pk >> 16)
                                                : (unsigned short)(pk & 0xffff);
                As[grow][gcol] = __builtin_bit_cast(f16, bits);
            }
        }
#pragma unroll
    for (int i = 0; i < 8; ++i) {
        int row = r0 + 16 * i;
        *(f16x8*)&Bs[row][seg * 8] = rb[i];       // W1t prefetched during e=3
    }
    __syncthreads();

    // ---------------- phase 2: fout_tile = h @ W1t, K = 128 ----------------
    f32x4 acc2[4][4];
#pragma unroll
    for (int r = 0; r < 4; ++r)
#pragma unroll
        for (int c = 0; c < 4; ++c) acc2[r][c] = (f32x4){0.f, 0.f, 0.f, 0.f};

#pragma unroll
    for (int t = 0; t < 4; ++t) {
        const int k0 = t * 32 + quad * 8;
        f16x8 af[4], bf[4];
#pragma unroll
        for (int r = 0; r < 4; ++r)
            af[r] = *(const f16x8*)&As[wr * 64 + r * 16 + lm][k0];
#pragma unroll
        for (int c = 0; c < 4; ++c)
            bf[c] = *(const f16x8*)&Bs[wc * 64 + c * 16 + lm][k0];
#pragma unroll
        for (int r = 0; r < 4; ++r)
#pragma unroll
            for (int c = 0; c < 4; ++c)
                acc2[r][c] = __builtin_amdgcn_mfma_f32_16x16x32_f16(
                    af[r], bf[c], acc2[r][c], 0, 0, 0);
    }
    __syncthreads();                              // As reads done, reuse for epilogue

    // epilogue: bias, scatter to As, then coalesced 16B stores
#pragma unroll
    for (int r = 0; r < 4; ++r)
#pragma unroll
        for (int c = 0; c < 4; ++c) {
            int gcol = wc * 64 + c * 16 + lm;
#pragma unroll
            for (int reg = 0; reg < 4; ++reg) {
                int grow = wr * 64 + r * 16 + quad * 4 + reg;
                As[grow][gcol] = (f16)(acc2[r][c][reg] + bb1[c]);
            }
        }
    __syncthreads();
#pragma unroll
    for (int i = 0; i < 8; ++i) {
        int row = r0 + 16 * i;
        *(f16x8*)&fout[(size_t)(bm + row) * D + seg * 8] =
            *(const f16x8*)&As[row][seg * 8];
    }
}

// ---------- readout: per-segment mean + pairwise dot ----------
__global__ __launch_bounds__(256) void readout_f16(
    const f16* __restrict__ feats, const float* __restrict__ out_bias,
    float* __restrict__ logits)
{
    __shared__ float ms[2][128];
    const int b   = blockIdx.x;
    const int tid = threadIdx.x;
    const int side = tid >> 7, d = tid & 127;

    const f16* base = feats + ((size_t)b * 128 + side * 64) * D + d;
    float s = 0.f;
#pragma unroll 8
    for (int n = 0; n < 64; ++n) s += (float)base[(size_t)n * D];
    ms[side][d] = s * (1.0f / 64.0f);
    __syncthreads();

    if (tid < 64) {
        float v = ms[0][tid] * ms[1][tid] + ms[0][tid + 64] * ms[1][tid + 64];
#pragma unroll
        for (int off = 32; off; off >>= 1) v += __shfl_down(v, off);
        if (tid == 0) logits[b] = v + out_bias[0];
    }
}

extern "C" void kernel_launch(void* const* d_in, const int* in_sizes, int n_in,
                              void* d_out, int out_size, void* d_ws, size_t ws_size,
                              hipStream_t stream) {
    const int*   node_idx  = (const int*)d_in[0];
    const int*   neighbors = (const int*)d_in[1];
    const float* emb       = (const float*)d_in[3];
    const float* W0        = (const float*)d_in[4];
    const float* b0        = (const float*)d_in[5];
    const float* W1        = (const float*)d_in[6];
    const float* b1        = (const float*)d_in[7];
    const float* out_bias  = (const float*)d_in[8];
    float*       logits    = (float*)d_out;

    const size_t NP1 = (size_t)N_NODES + 1;                  // +1 zero pad row
    f16* feats_a = (f16*)d_ws;                               // ~32 MB
    f16* feats_b = feats_a + NP1 * D;                        // ~32 MB
    f16* W0t     = feats_b + NP1 * D;                        // 512 KB
    f16* W1t     = W0t + (size_t)NLAYERS * 512 * 128;        // 128 KB

    prep_weights<<<80, 256, 0, stream>>>(W0, W1, W0t, W1t);
    embed_f16<<<16385, 256, 0, stream>>>(node_idx, emb, feats_a, feats_b);

    f16* fin = feats_a; f16* fout = feats_b;
    for (int l = 0; l < NLAYERS; ++l) {
        layer_fused<<<N_NODES / 128, 256, 0, stream>>>(
            fin, fout, neighbors,
            W0t + (size_t)l * 512 * 128, b0 + (size_t)l * 128,
            W1t + (size_t)l * 128 * 128, b1 + (size_t)l * 128);
        f16* t = fin; fin = fout; fout = t;
    }
    // after 4 swaps the final features are back in feats_a
    readout_f16<<<N_NODES / 128, 256, 0, stream>>>(feats_a, out_bias, logits);
}

// Round 4
// 238.095 us; speedup vs baseline: 4.9410x; 1.0284x over previous
//
#include <hip/hip_runtime.h>

#define N_NODES 131072
#define D 128
#define NLAYERS 4
#define AS_STRIDE 136   // 128 + 8 f16 pad -> 272 B rows; 16B-aligned, 2-way max on b128

typedef _Float16 f16;
typedef _Float16 f16x8 __attribute__((ext_vector_type(8)));
typedef float f32x4 __attribute__((ext_vector_type(4)));

// ---------- prep: W0t[l][n][k]=f16(W0[l][k][n]), W1t likewise; +zero pad rows ----------
__global__ __launch_bounds__(256) void prep_weights(
    const float* __restrict__ W0, const float* __restrict__ W1,
    f16* __restrict__ W0t, f16* __restrict__ W1t,
    f16* __restrict__ fa, f16* __restrict__ fb)
{
    __shared__ float T[64][65];
    int b = blockIdx.x;
    const int tid = threadIdx.x;
    if (b == 80) {                      // zero the padding row (id N_NODES) of both buffers
        if (tid < 32) {
            f16x8 z = {0, 0, 0, 0, 0, 0, 0, 0};
            f16* base = (tid >> 4) ? fb : fa;
            *(f16x8*)&base[(size_t)N_NODES * D + (tid & 15) * 8] = z;
        }
        return;
    }
    const float* src; f16* dst; int K, tk, tn;
    if (b < 64) {                       // W0: 4 layers x (8 k-tiles x 2 n-tiles)
        int l = b >> 4; tk = (b >> 1) & 7; tn = b & 1;
        src = W0 + (size_t)l * 512 * 128; dst = W0t + (size_t)l * 128 * 512; K = 512;
    } else {                            // W1: 4 layers x (2 x 2)
        int bb = b - 64; int l = bb >> 2; tk = (bb >> 1) & 1; tn = bb & 1;
        src = W1 + (size_t)l * 128 * 128; dst = W1t + (size_t)l * 128 * 128; K = 128;
    }
#pragma unroll
    for (int i = 0; i < 16; ++i) {
        int u = tid + 256 * i;          // 4096 elems
        int kk = u >> 6, nn = u & 63;
        T[kk][nn] = src[(size_t)(tk * 64 + kk) * 128 + tn * 64 + nn];
    }
    __syncthreads();
#pragma unroll
    for (int i = 0; i < 16; ++i) {
        int u = tid + 256 * i;
        int nn = u >> 6, kk = u & 63;
        dst[(size_t)(tn * 64 + nn) * K + tk * 64 + kk] = (f16)T[kk][nn];
    }
}

// ======================= shared MFMA tile compute =======================
#define COMPUTE_STAGE(ACC)                                                   \
    _Pragma("unroll")                                                        \
    for (int t = 0; t < 4; ++t) {                                            \
        const int k0 = t * 32 + quad * 8;                                    \
        f16x8 af[4], bf[4];                                                  \
        _Pragma("unroll")                                                    \
        for (int r = 0; r < 4; ++r)                                          \
            af[r] = *(const f16x8*)&As[wr * 64 + r * 16 + lm][k0];           \
        _Pragma("unroll")                                                    \
        for (int c = 0; c < 4; ++c)                                          \
            bf[c] = *(const f16x8*)&Bs[wc * 64 + c * 16 + lm][k0];           \
        _Pragma("unroll")                                                    \
        for (int r = 0; r < 4; ++r)                                          \
            _Pragma("unroll")                                                \
            for (int c = 0; c < 4; ++c)                                      \
                ACC[r][c] = __builtin_amdgcn_mfma_f32_16x16x32_f16(          \
                    af[r], bf[c], ACC[r][c], 0, 0, 0);                       \
    }

// phase-2 + epilogue shared tail (h in hpk, W1 tile in rb)
#define TAIL_PHASE2_EPILOGUE()                                               \
    /* scatter h (C-layout) into As as phase-2 A operand; W1t -> Bs */       \
    _Pragma("unroll")                                                        \
    for (int r = 0; r < 4; ++r)                                              \
        _Pragma("unroll")                                                    \
        for (int c = 0; c < 4; ++c) {                                        \
            int gcol = wc * 64 + c * 16 + lm;                                \
            _Pragma("unroll")                                                \
            for (int reg = 0; reg < 4; ++reg) {                              \
                int grow = wr * 64 + r * 16 + quad * 4 + reg;                \
                unsigned pk = hpk[r][c][reg >> 1];                           \
                unsigned short bits = (reg & 1) ? (unsigned short)(pk >> 16) \
                                                : (unsigned short)(pk & 0xffff); \
                As[grow][gcol] = __builtin_bit_cast(f16, bits);              \
            }                                                                \
        }                                                                    \
    _Pragma("unroll")                                                        \
    for (int i = 0; i < 8; ++i) {                                            \
        int row = r0 + 16 * i;                                               \
        *(f16x8*)&Bs[row][seg * 8] = rb[i];                                  \
    }                                                                        \
    __syncthreads();                                                         \
    f32x4 acc2[4][4];                                                        \
    _Pragma("unroll")                                                        \
    for (int r = 0; r < 4; ++r)                                              \
        _Pragma("unroll")                                                    \
        for (int c = 0; c < 4; ++c) acc2[r][c] = (f32x4){0.f, 0.f, 0.f, 0.f};\
    COMPUTE_STAGE(acc2)                                                      \
    __syncthreads();                                                         \
    _Pragma("unroll")                                                        \
    for (int r = 0; r < 4; ++r)                                              \
        _Pragma("unroll")                                                    \
        for (int c = 0; c < 4; ++c) {                                        \
            int gcol = wc * 64 + c * 16 + lm;                                \
            _Pragma("unroll")                                                \
            for (int reg = 0; reg < 4; ++reg) {                              \
                int grow = wr * 64 + r * 16 + quad * 4 + reg;                \
                As[grow][gcol] = (f16)(acc2[r][c][reg] + bb1[c]);            \
            }                                                                \
        }                                                                    \
    __syncthreads();                                                         \
    _Pragma("unroll")                                                        \
    for (int i = 0; i < 8; ++i) {                                            \
        int row = r0 + 16 * i;                                               \
        *(f16x8*)&fout[(size_t)(bm + row) * D + seg * 8] =                   \
            *(const f16x8*)&As[row][seg * 8];                                \
    }

#define PACK_H()                                                             \
    unsigned int hpk[4][4][2];                                               \
    _Pragma("unroll")                                                        \
    for (int c = 0; c < 4; ++c) {                                            \
        _Pragma("unroll")                                                    \
        for (int r = 0; r < 4; ++r) {                                        \
            _Pragma("unroll")                                                \
            for (int p = 0; p < 2; ++p) {                                    \
                float v0 = fmaxf(acc1[r][c][2 * p]     + bb0[c], 0.f);       \
                float v1 = fmaxf(acc1[r][c][2 * p + 1] + bb0[c], 0.f);       \
                unsigned short u0 = __builtin_bit_cast(unsigned short, (f16)v0); \
                unsigned short u1 = __builtin_bit_cast(unsigned short, (f16)v1); \
                hpk[r][c][p] = ((unsigned)u1 << 16) | u0;                    \
            }                                                                \
        }                                                                    \
    }

// ---------- layer 0: gather straight from emb via node_idx (L2-resident) ----------
__global__ __launch_bounds__(256, 2) void layer_emb(
    const int* __restrict__ node_idx, const float* __restrict__ emb,
    f16* __restrict__ fout, const int* __restrict__ neighbors,
    const f16* __restrict__ W0t, const float* __restrict__ b0,
    const f16* __restrict__ W1t, const float* __restrict__ b1)
{
    __shared__ f16 As[128][AS_STRIDE];
    __shared__ f16 Bs[128][AS_STRIDE];
    __shared__ int nbr_s[512];

    const int tid  = threadIdx.x;
    const int bm   = blockIdx.x * 128;
    const int lane = tid & 63;
    const int wave = tid >> 6;
    const int wr = wave >> 1, wc = wave & 1;
    const int quad = lane >> 4, lm = lane & 15;
    const int seg = tid & 15, r0 = tid >> 4;

    nbr_s[tid]       = neighbors[bm * 4 + tid];
    nbr_s[tid + 256] = neighbors[bm * 4 + 256 + tid];

    float bb0[4], bb1[4];
#pragma unroll
    for (int c = 0; c < 4; ++c) {
        bb0[c] = b0[wc * 64 + c * 16 + lm];
        bb1[c] = b1[wc * 64 + c * 16 + lm];
    }

    float4 rg[8][2];
    f16x8 rb[8];
    __syncthreads();

    // issue gather stage 0 (emb rows are f32: 512B -> 2 float4 per thread)
#pragma unroll
    for (int i = 0; i < 8; ++i) {
        int row = r0 + 16 * i;
        int nbr = nbr_s[row * 4 + 0];
        float4 z = make_float4(0.f, 0.f, 0.f, 0.f);
        rg[i][0] = z; rg[i][1] = z;
        if (nbr < N_NODES) {
            int tok = node_idx[nbr];
            const float4* p = (const float4*)emb + (size_t)tok * 32 + seg * 2;
            rg[i][0] = p[0]; rg[i][1] = p[1];
        }
    }
#pragma unroll
    for (int i = 0; i < 8; ++i) {
        int row = r0 + 16 * i;
        rb[i] = *(const f16x8*)&W0t[(size_t)row * 512 + seg * 8];
    }
#pragma unroll
    for (int i = 0; i < 8; ++i) {
        int row = r0 + 16 * i;
        float4 a = rg[i][0], bq = rg[i][1];
        f16x8 v = { (f16)a.x, (f16)a.y, (f16)a.z, (f16)a.w,
                    (f16)bq.x, (f16)bq.y, (f16)bq.z, (f16)bq.w };
        *(f16x8*)&As[row][seg * 8] = v;
        *(f16x8*)&Bs[row][seg * 8] = rb[i];
    }
    __syncthreads();
#pragma unroll
    for (int i = 0; i < 8; ++i) {
        int row = r0 + 16 * i;
        rb[i] = *(const f16x8*)&W0t[(size_t)row * 512 + 128 + seg * 8];
    }

    f32x4 acc1[4][4];
#pragma unroll
    for (int r = 0; r < 4; ++r)
#pragma unroll
        for (int c = 0; c < 4; ++c) acc1[r][c] = (f32x4){0.f, 0.f, 0.f, 0.f};

#pragma unroll
    for (int e = 0; e < 4; ++e) {
        if (e < 3) {
#pragma unroll
            for (int i = 0; i < 8; ++i) {
                int row = r0 + 16 * i;
                int nbr = nbr_s[row * 4 + e + 1];
                float4 z = make_float4(0.f, 0.f, 0.f, 0.f);
                rg[i][0] = z; rg[i][1] = z;
                if (nbr < N_NODES) {
                    int tok = node_idx[nbr];
                    const float4* p = (const float4*)emb + (size_t)tok * 32 + seg * 2;
                    rg[i][0] = p[0]; rg[i][1] = p[1];
                }
            }
        }
        COMPUTE_STAGE(acc1)
        __syncthreads();
        if (e < 3) {
#pragma unroll
            for (int i = 0; i < 8; ++i) {
                int row = r0 + 16 * i;
                float4 a = rg[i][0], bq = rg[i][1];
                f16x8 v = { (f16)a.x, (f16)a.y, (f16)a.z, (f16)a.w,
                            (f16)bq.x, (f16)bq.y, (f16)bq.z, (f16)bq.w };
                *(f16x8*)&As[row][seg * 8] = v;
                *(f16x8*)&Bs[row][seg * 8] = rb[i];
            }
            __syncthreads();
#pragma unroll
            for (int i = 0; i < 8; ++i) {
                int row = r0 + 16 * i;
                rb[i] = (e < 2)
                    ? *(const f16x8*)&W0t[(size_t)row * 512 + (e + 2) * 128 + seg * 8]
                    : *(const f16x8*)&W1t[(size_t)row * 128 + seg * 8];
            }
        }
    }

    PACK_H()
    TAIL_PHASE2_EPILOGUE()
}

// ---------- layers 1..3: f16 gather, 2-deep register prefetch ----------
__global__ __launch_bounds__(256, 2) void layer_mid(
    const f16* __restrict__ fin, f16* __restrict__ fout,
    const int* __restrict__ neighbors,
    const f16* __restrict__ W0t, const float* __restrict__ b0,
    const f16* __restrict__ W1t, const float* __restrict__ b1)
{
    __shared__ f16 As[128][AS_STRIDE];
    __shared__ f16 Bs[128][AS_STRIDE];
    __shared__ int nbr_s[512];

    const int tid  = threadIdx.x;
    const int bm   = blockIdx.x * 128;
    const int lane = tid & 63;
    const int wave = tid >> 6;
    const int wr = wave >> 1, wc = wave & 1;
    const int quad = lane >> 4, lm = lane & 15;
    const int seg = tid & 15, r0 = tid >> 4;

    nbr_s[tid]       = neighbors[bm * 4 + tid];
    nbr_s[tid + 256] = neighbors[bm * 4 + 256 + tid];

    float bb0[4], bb1[4];
#pragma unroll
    for (int c = 0; c < 4; ++c) {
        bb0[c] = b0[wc * 64 + c * 16 + lm];
        bb1[c] = b1[wc * 64 + c * 16 + lm];
    }

    f16x8 ra0[8], ra1[8], rb[8];
    __syncthreads();

    // issue gather stages 0 and 1, weights stage 0
#pragma unroll
    for (int i = 0; i < 8; ++i) {
        int row = r0 + 16 * i;
        ra0[i] = *(const f16x8*)&fin[(size_t)nbr_s[row * 4 + 0] * D + seg * 8];
    }
#pragma unroll
    for (int i = 0; i < 8; ++i) {
        int row = r0 + 16 * i;
        ra1[i] = *(const f16x8*)&fin[(size_t)nbr_s[row * 4 + 1] * D + seg * 8];
    }
#pragma unroll
    for (int i = 0; i < 8; ++i) {
        int row = r0 + 16 * i;
        rb[i] = *(const f16x8*)&W0t[(size_t)row * 512 + seg * 8];
    }
    // consume stage 0
#pragma unroll
    for (int i = 0; i < 8; ++i) {
        int row = r0 + 16 * i;
        *(f16x8*)&As[row][seg * 8] = ra0[i];
        *(f16x8*)&Bs[row][seg * 8] = rb[i];
    }
    __syncthreads();
#pragma unroll
    for (int i = 0; i < 8; ++i) {
        int row = r0 + 16 * i;
        rb[i] = *(const f16x8*)&W0t[(size_t)row * 512 + 128 + seg * 8];
    }

    f32x4 acc1[4][4];
#pragma unroll
    for (int r = 0; r < 4; ++r)
#pragma unroll
        for (int c = 0; c < 4; ++c) acc1[r][c] = (f32x4){0.f, 0.f, 0.f, 0.f};

#pragma unroll
    for (int e = 0; e < 4; ++e) {
        // issue gather for stage e+2 into the buffer freed one stage ago
        if (e == 0) {
#pragma unroll
            for (int i = 0; i < 8; ++i) {
                int row = r0 + 16 * i;
                ra0[i] = *(const f16x8*)&fin[(size_t)nbr_s[row * 4 + 2] * D + seg * 8];
            }
        } else if (e == 1) {
#pragma unroll
            for (int i = 0; i < 8; ++i) {
                int row = r0 + 16 * i;
                ra1[i] = *(const f16x8*)&fin[(size_t)nbr_s[row * 4 + 3] * D + seg * 8];
            }
        }
        COMPUTE_STAGE(acc1)
        __syncthreads();
        if (e < 3) {
#pragma unroll
            for (int i = 0; i < 8; ++i) {
                int row = r0 + 16 * i;
                *(f16x8*)&As[row][seg * 8] = (e & 1) ? ra0[i] : ra1[i];
                *(f16x8*)&Bs[row][seg * 8] = rb[i];
            }
            __syncthreads();
#pragma unroll
            for (int i = 0; i < 8; ++i) {
                int row = r0 + 16 * i;
                rb[i] = (e < 2)
                    ? *(const f16x8*)&W0t[(size_t)row * 512 + (e + 2) * 128 + seg * 8]
                    : *(const f16x8*)&W1t[(size_t)row * 128 + seg * 8];
            }
        }
    }

    PACK_H()
    TAIL_PHASE2_EPILOGUE()
}

// ---------- readout: per-segment mean + pairwise dot ----------
__global__ __launch_bounds__(256) void readout_f16(
    const f16* __restrict__ feats, const float* __restrict__ out_bias,
    float* __restrict__ logits)
{
    __shared__ float ms[2][128];
    const int b   = blockIdx.x;
    const int tid = threadIdx.x;
    const int side = tid >> 7, d = tid & 127;

    const f16* base = feats + ((size_t)b * 128 + side * 64) * D + d;
    float s = 0.f;
#pragma unroll 8
    for (int n = 0; n < 64; ++n) s += (float)base[(size_t)n * D];
    ms[side][d] = s * (1.0f / 64.0f);
    __syncthreads();

    if (tid < 64) {
        float v = ms[0][tid] * ms[1][tid] + ms[0][tid + 64] * ms[1][tid + 64];
#pragma unroll
        for (int off = 32; off; off >>= 1) v += __shfl_down(v, off);
        if (tid == 0) logits[b] = v + out_bias[0];
    }
}

extern "C" void kernel_launch(void* const* d_in, const int* in_sizes, int n_in,
                              void* d_out, int out_size, void* d_ws, size_t ws_size,
                              hipStream_t stream) {
    const int*   node_idx  = (const int*)d_in[0];
    const int*   neighbors = (const int*)d_in[1];
    const float* emb       = (const float*)d_in[3];
    const float* W0        = (const float*)d_in[4];
    const float* b0        = (const float*)d_in[5];
    const float* W1        = (const float*)d_in[6];
    const float* b1        = (const float*)d_in[7];
    const float* out_bias  = (const float*)d_in[8];
    float*       logits    = (float*)d_out;

    const size_t NP1 = (size_t)N_NODES + 1;                  // +1 zero pad row
    f16* feats_a = (f16*)d_ws;                               // ~32 MB
    f16* feats_b = feats_a + NP1 * D;                        // ~32 MB
    f16* W0t     = feats_b + NP1 * D;                        // 512 KB
    f16* W1t     = W0t + (size_t)NLAYERS * 512 * 128;        // 128 KB

    prep_weights<<<81, 256, 0, stream>>>(W0, W1, W0t, W1t, feats_a, feats_b);

    // layer 0: emb-gather (L2-resident table) -> feats_a
    layer_emb<<<N_NODES / 128, 256, 0, stream>>>(
        node_idx, emb, feats_a, neighbors, W0t, b0, W1t, b1);

    // layers 1..3: a->b->a->b
    f16* fin = feats_a; f16* fout = feats_b;
    for (int l = 1; l < NLAYERS; ++l) {
        layer_mid<<<N_NODES / 128, 256, 0, stream>>>(
            fin, fout, neighbors,
            W0t + (size_t)l * 512 * 128, b0 + (size_t)l * 128,
            W1t + (size_t)l * 128 * 128, b1 + (size_t)l * 128);
        f16* t = fin; fin = fout; fout = t;
    }
    readout_f16<<<N_NODES / 128, 256, 0, stream>>>(feats_b, out_bias, logits);
}